// Round 16
// baseline (111.764 us; speedup 1.0000x reference)
//
#include <hip/hip_runtime.h>
#include <hip/hip_bf16.h>
#include <cstdint>

typedef __attribute__((ext_vector_type(8))) short bf16x8;
typedef __attribute__((ext_vector_type(4))) float f32x4;

#define T_SEQ 2048
#define NB    8
#define CDIM  1024
#define HDIM  128
#define NQB   32      // q-blocks of 64 rows per batch

__device__ __forceinline__ float exp2fast(float x) { return __builtin_amdgcn_exp2f(x); }
__device__ __forceinline__ float log2fast(float x) { return __builtin_amdgcn_logf(x); }

__device__ __forceinline__ short f2bf(float f) {
  unsigned u = __float_as_uint(f);
  u += 0x7fff + ((u >> 16) & 1);   // RNE
  return (short)(u >> 16);
}

__device__ __forceinline__ float bf2f(short s) {
  return __uint_as_float(((unsigned)(unsigned short)s) << 16);
}

__device__ __forceinline__ unsigned pk2(float a, float b) {
  return (unsigned)(unsigned short)f2bf(a) | ((unsigned)(unsigned short)f2bf(b) << 16);
}

__device__ __forceinline__ void gload_lds16(const void* gsrc, void* lds_base_uniform) {
  __builtin_amdgcn_global_load_lds(
      (const __attribute__((address_space(1))) unsigned int*)gsrc,
      (__attribute__((address_space(3))) unsigned int*)lds_base_uniform,
      16, 0, 0);
}

// ---------------- bias table (log2 domain): tab[d] = log2(sum_g alpha_g * g^d + 1e-8) --
__global__ void msta_bias_kernel(const float* gfl, const float* gml, const float* gsl,
                                 const float* al, float* tab) {
  int d = blockIdx.x * 256 + threadIdx.x;
  if (d >= T_SEQ) return;
  float gf = 0.30f / (1.f + __expf(-gfl[0])) + 0.60f;
  float gm = 0.15f / (1.f + __expf(-gml[0])) + 0.85f;
  float gs = 0.05f / (1.f + __expf(-gsl[0])) + 0.95f;
  float a0 = al[0], a1 = al[1], a2 = al[2];
  float mx = fmaxf(a0, fmaxf(a1, a2));
  float e0 = __expf(a0 - mx), e1 = __expf(a1 - mx), e2 = __expf(a2 - mx);
  float inv = 1.f / (e0 + e1 + e2);
  float fd = (float)d;
  float mix = e0 * inv * exp2fast(fd * log2fast(gf))
            + e1 * inv * exp2fast(fd * log2fast(gm))
            + e2 * inv * exp2fast(fd * log2fast(gs));
  tab[d] = log2fast(mix + 1e-8f);
}

// ---------------- W pack: MFMA-B-fragment order + bf16; Wq gets H^-0.5*log2(e) ---------
__global__ void msta_wt_kernel(const float* Wq, const float* Wk, const float* Wv, short* wt) {
  int idx = blockIdx.x * 256 + threadIdx.x;      // [0, 3*128*1024)
  int m = idx >> 17;
  int r = idx & 131071;
  int n = r >> 10;
  int kv = r & 1023;
  const float* W = (m == 0) ? Wq : ((m == 1) ? Wk : Wv);
  float v = W[kv * HDIM + n];
  if (m == 0) v *= 0.08838834764831845f * 1.4426950408889634f;  // H^-0.5 * log2(e)
  int c  = m * 128 + n;
  int t  = kv >> 6, kk = (kv >> 5) & 1, hi = (kv >> 3) & 3, e = kv & 7;
  int cf = c >> 4,  lo = c & 15;
  int si = (((t * 2 + kk) * 24 + cf) * 64 + (hi * 16 + lo)) * 8 + e;
  wt[si] = f2bf(v);
}

// ---------------- QKV part A: GEMM only, raw fragment dump (measurement split) ---------
// BM=32 rows x 192 cols per block (col-split x2), grid 1024 = 4 blocks/CU = 16 waves/CU.
// No epilogue bounce: acc dumped coalesced in native fragment order to scratch.
__global__ __launch_bounds__(256) void msta_qkv_gemm(
    const float* __restrict__ x, const short* __restrict__ wt,
    short* __restrict__ scratch) {
  __shared__ short lds[32 * 64];       // 4 KB x tile

  const int tid  = threadIdx.x;
  const int lane = tid & 63;
  const int w    = tid >> 6;
  const int lo   = lane & 15, hi = lane >> 4;
  const int bid  = blockIdx.x;          // 1024 = 8 XCDs * 128
  const int xcd  = bid & 7;
  const int j    = bid >> 3;            // 0..127
  const int cid  = j & 1;               // column half (cf 0..11 or 12..23)
  const int rowblk = j >> 1;            // 0..63
  const int r0   = (xcd * 64 + rowblk) * 32;   // batch b rows live on XCD b

  // x staging: granule g = tid: row=g>>3 (0..31), c8=g&7
  const int xrow = tid >> 3, xc8 = tid & 7;
  const float* xsrc = x + (size_t)(r0 + xrow) * CDIM + xc8 * 8;
  const int xdst = xrow * 128 + ((xc8 * 16) ^ ((xrow & 7) << 4));   // byte offset

  f32x4 acc[2][3];
  #pragma unroll
  for (int f = 0; f < 2; f++)
    #pragma unroll
    for (int jf = 0; jf < 3; jf++)
      acc[f][jf] = (f32x4){0.f, 0.f, 0.f, 0.f};

  f32x4 xa, xb;
  auto xload = [&](int t) {
    const f32x4* s = (const f32x4*)(xsrc + t * 64);
    xa = __builtin_nontemporal_load(s);          // x has zero reuse: NT load
    xb = __builtin_nontemporal_load(s + 1);
  };
  auto xwrite = [&]() {
    uint4 u;
    u.x = pk2(xa.x, xa.y); u.y = pk2(xa.z, xa.w);
    u.z = pk2(xb.x, xb.y); u.w = pk2(xb.z, xb.w);
    *(uint4*)((char*)lds + xdst) = u;
  };

  xload(0);
  for (int t = 0; t < 16; ++t) {
    xwrite();
    __syncthreads();                       // x tile ready
    if (t < 15) xload(t + 1);              // issue next x reads early

    bf16x8 Bv[2][3];
    #pragma unroll
    for (int kk = 0; kk < 2; kk++)
      #pragma unroll
      for (int jf = 0; jf < 3; jf++) {
        int si = (((t * 2 + kk) * 24 + (cid * 12 + w * 3 + jf)) * 64 + lane) * 8;
        Bv[kk][jf] = *(const bf16x8*)(wt + si);
      }

    #pragma unroll
    for (int kk = 0; kk < 2; kk++) {
      bf16x8 A[2];
      #pragma unroll
      for (int f = 0; f < 2; f++) {
        int r = f * 16 + lo;
        A[f] = *(const bf16x8*)((const char*)lds + r * 128 +
                                ((kk * 64 + hi * 16) ^ ((r & 7) << 4)));
      }
      #pragma unroll
      for (int jf = 0; jf < 3; jf++) {
        acc[0][jf] = __builtin_amdgcn_mfma_f32_16x16x32_bf16(A[0], Bv[kk][jf], acc[0][jf], 0, 0, 0);
        acc[1][jf] = __builtin_amdgcn_mfma_f32_16x16x32_bf16(A[1], Bv[kk][jf], acc[1][jf], 0, 0, 0);
      }
    }
    __syncthreads();                       // x tile consumed
  }

  // raw dump: frag (f,jf) -> scratch[bid][frag][tid][0..3], coalesced uint2 per lane
  short* sb = scratch + (size_t)bid * 6144;
  #pragma unroll
  for (int f = 0; f < 2; f++) {
    #pragma unroll
    for (int jf = 0; jf < 3; jf++) {
      f32x4 a = acc[f][jf];
      uint2 pr;
      pr.x = pk2(a[0], a[1]);
      pr.y = pk2(a[2], a[3]);
      *(uint2*)(sb + (f * 3 + jf) * 1024 + tid * 4) = pr;
    }
  }
}

// scratch element for (row-block rb=xcd*64+rowblk, row 0..31, global col c 0..383)
__device__ __forceinline__ short read_scr(const short* scratch, int rb, int row, int c) {
  int xcd = rb >> 6, rowblk = rb & 63;
  int cid = c / 192;
  int cl  = c - cid * 192;
  int w_  = cl / 48;
  int jf  = (cl % 48) >> 4;
  int lo_ = cl & 15;
  int f_  = row >> 4;
  int hi_ = (row >> 2) & 3;
  int rg  = row & 3;
  int bid = (((rowblk << 1) + cid) << 3) + xcd;
  return scratch[(((size_t)bid * 6 + f_ * 3 + jf) << 10) + ((w_ * 64 + hi_ * 16 + lo_) << 2) + rg];
}

// ---------------- QKV part B: relayout scratch -> q, k, vt (coalesced writes) ----------
__global__ __launch_bounds__(256) void msta_relayout(
    const short* __restrict__ scratch,
    short* __restrict__ q, short* __restrict__ k, short* __restrict__ vt) {
  const int tid = threadIdx.x;
  if (blockIdx.x < 2048) {
    // q & k: 512 rb x 32 rows x 32 col-groups(8)
    int g   = blockIdx.x * 256 + tid;
    int rb  = g >> 10;
    int rem = g & 1023;
    int row = rem >> 5;
    int cg  = rem & 31;
    int r0  = rb * 32;
    bf16x8 v;
    #pragma unroll
    for (int i = 0; i < 8; i++)
      v[i] = read_scr(scratch, rb, row, cg * 8 + i);
    if (cg < 16)
      *(bf16x8*)(q + (size_t)(r0 + row) * HDIM + cg * 8) = v;
    else
      *(bf16x8*)(k + (size_t)(r0 + row) * HDIM + (cg - 16) * 8) = v;
  } else {
    // vt: 512 rb x 128 h x 4 row-groups(8)
    int g   = (blockIdx.x - 2048) * 256 + tid;
    int rb  = g >> 9;
    int rem = g & 511;
    int h   = rem >> 2;
    int rowg = rem & 3;
    int r0  = rb * 32;
    int bb  = r0 >> 11, tt0 = r0 & 2047;
    bf16x8 v;
    #pragma unroll
    for (int i = 0; i < 8; i++)
      v[i] = read_scr(scratch, rb, rowg * 8 + i, 256 + h);
    *(bf16x8*)(vt + ((size_t)bb * HDIM + h) * T_SEQ + tt0 + rowg * 8) = v;
  }
}

// ---------------- flash attention: batch==XCD, 4 waves, KT=64, single-buffer -----------
template <int SP>
__global__ __launch_bounds__(256) void msta_attn_kernel(
    const short* __restrict__ q, const short* __restrict__ kg,
    const short* __restrict__ vt, const float* __restrict__ bias_tab,
    float* __restrict__ out, short* __restrict__ opart, float2* __restrict__ ml) {
  __shared__ short Ks[64 * 128];      // [s][h] swizzled, 16 KB
  __shared__ short Vs[128 * 64];      // [h][s] swizzled, 16 KB
  __shared__ short Ps[4][16 * 64];    // per-wave P, swizzled, 8 KB

  const int tid  = threadIdx.x;
  const int lane = tid & 63;
  const int w    = tid >> 6;
  const int lo   = lane & 15, hi = lane >> 4;

  const int idx = blockIdx.x;
  const int b   = idx & 7;                      // batch == XCD (hw: XCD = bid % 8)
  const int r_  = idx >> 3;                     // 0..NQB*SP-1, within-XCD
  const int qb  = (NQB - 1) - r_ / SP;          // LPT: longest q-blocks first
  const int sp  = r_ % SP;
  const int q0  = qb * 64;

  const int nt  = qb + 1;                       // causal tile count for this q-block
  const int csz = (nt + SP - 1) / SP;
  const int t0  = sp * csz;
  const int t1  = (t0 + csz < nt) ? (t0 + csz) : nt;

  if (t0 >= t1) {                               // empty chunk: flag l=0 and exit
    if (SP > 1 && lane < 16) {
      int t = q0 + w * 16 + lane;
      ml[((size_t)sp * NB + b) * T_SEQ + t] = make_float2(-1e30f, 0.f);
    }
    return;
  }

  const short* kb = kg + (size_t)b * T_SEQ * HDIM;
  const short* vb = vt + (size_t)b * HDIM * T_SEQ;

  // Q fragments in registers (16 rows per wave; Wq carries H^-0.5*log2e)
  bf16x8 qf[4];
  const short* qbase = q + ((size_t)b * T_SEQ + q0 + w * 16 + lo) * HDIM;
  #pragma unroll
  for (int ks = 0; ks < 4; ks++)
    qf[ks] = *(const bf16x8*)(qbase + ks * 32 + hi * 8);

  // staging pointers at the LAST tile; decremented per stage() call (descending)
  const int s0i = (t1 - 1) * 64;
  const char* ksrc[4];
  const char* vsrc[4];
  #pragma unroll
  for (int i = 0; i < 4; i++) {
    int G = (w * 4 + i) * 64 + lane;
    { int r = G >> 4, g = G & 15;
      int c = (g & 8) | ((g & 7) ^ (r & 7));
      ksrc[i] = (const char*)(kb + (size_t)(s0i + r) * HDIM) + c * 16; }
    { int r = G >> 3, g = G & 7;
      int c = g ^ (r & 7);
      vsrc[i] = (const char*)(vb + (size_t)r * T_SEQ + s0i) + c * 16; }
  }
  auto stage = [&]() {
    #pragma unroll
    for (int i = 0; i < 4; i++) {
      gload_lds16(ksrc[i], (char*)Ks + (w * 4 + i) * 1024);
      ksrc[i] -= 64 * HDIM * 2;
      gload_lds16(vsrc[i], (char*)Vs + (w * 4 + i) * 1024);
      vsrc[i] -= 128;
    }
  };

  f32x4 oacc[8];
  #pragma unroll
  for (int jo = 0; jo < 8; jo++) oacc[jo] = (f32x4){0.f, 0.f, 0.f, 0.f};
  float mrow[4], lrow[4];
  #pragma unroll
  for (int rg = 0; rg < 4; rg++) { mrow[rg] = -1e30f; lrow[rg] = 0.f; }

  stage();
  __syncthreads();                               // drains vmcnt: tile t1-1 resident

  for (int t = t1 - 1; t >= t0; --t) {
    const int s0 = t * 64;

    // S = Q @ K^T   (16 x 64 per wave), log2 domain
    f32x4 sacc[4];
    #pragma unroll
    for (int jf = 0; jf < 4; jf++) sacc[jf] = (f32x4){0.f, 0.f, 0.f, 0.f};
    __builtin_amdgcn_s_setprio(1);
    #pragma unroll
    for (int ks = 0; ks < 4; ks++) {
      #pragma unroll
      for (int jf = 0; jf < 4; jf++) {
        int s = jf * 16 + lo;
        int byteoff = s * 256 + ((ks * 64 + hi * 16) ^ ((s & 7) << 4));
        bf16x8 kf = *(const bf16x8*)((const char*)Ks + byteoff);
        sacc[jf] = __builtin_amdgcn_mfma_f32_16x16x32_bf16(qf[ks], kf, sacc[jf], 0, 0, 0);
      }
    }
    __builtin_amdgcn_s_setprio(0);

    // bias + causal mask
    float sv[4][4];
    #pragma unroll
    for (int jf = 0; jf < 4; jf++) {
      #pragma unroll
      for (int rg = 0; rg < 4; rg++) {
        int i_ = q0 + w * 16 + hi * 4 + rg;
        int j_ = s0 + jf * 16 + lo;
        int d = i_ - j_;
        sv[jf][rg] = (d >= 0) ? (sacc[jf][rg] + bias_tab[d]) : -1e30f;
      }
    }

    // row max (within 16-lane group); defer-max: skip rescale unless max grew
    float mx[4];
    bool need = false;
    #pragma unroll
    for (int rg = 0; rg < 4; rg++) {
      float v = fmaxf(fmaxf(sv[0][rg], sv[1][rg]), fmaxf(sv[2][rg], sv[3][rg]));
      v = fmaxf(v, __shfl_xor(v, 1));
      v = fmaxf(v, __shfl_xor(v, 2));
      v = fmaxf(v, __shfl_xor(v, 4));
      v = fmaxf(v, __shfl_xor(v, 8));
      mx[rg] = v;
      need |= (v > mrow[rg]);
    }
    if (__any((int)need)) {
      #pragma unroll
      for (int rg = 0; rg < 4; rg++) {
        float mnew = fmaxf(mrow[rg], mx[rg]);
        float sc = exp2fast(mrow[rg] - mnew);
        mrow[rg] = mnew;
        lrow[rg] *= sc;
        #pragma unroll
        for (int jo = 0; jo < 8; jo++) oacc[jo][rg] *= sc;
      }
    }

    // P = exp2(sv - m) -> bf16 into per-wave LDS (A-layout bounce) + row sums
    float psum[4] = {0.f, 0.f, 0.f, 0.f};
    #pragma unroll
    for (int jf = 0; jf < 4; jf++) {
      #pragma unroll
      for (int rg = 0; rg < 4; rg++) {
        float p = exp2fast(sv[jf][rg] - mrow[rg]);
        psum[rg] += p;
        int prow = hi * 4 + rg;
        int pcol = jf * 16 + lo;
        int byteoff = prow * 128 + ((pcol * 2) ^ ((prow & 7) << 4));
        *(short*)((char*)Ps[w] + byteoff) = f2bf(p);
      }
    }
    #pragma unroll
    for (int rg = 0; rg < 4; rg++) {
      float s = psum[rg];
      s += __shfl_xor(s, 1); s += __shfl_xor(s, 2);
      s += __shfl_xor(s, 4); s += __shfl_xor(s, 8);
      lrow[rg] += s;
    }

    // O += P @ V
    __builtin_amdgcn_s_setprio(1);
    #pragma unroll
    for (int ks = 0; ks < 2; ks++) {
      int pbyte = lo * 128 + ((ks * 64 + hi * 16) ^ ((lo & 7) << 4));
      bf16x8 pf = *(const bf16x8*)((const char*)Ps[w] + pbyte);
      #pragma unroll
      for (int jo = 0; jo < 8; jo++) {
        int h = jo * 16 + lo;
        int vbyte = h * 128 + ((ks * 64 + hi * 16) ^ ((h & 7) << 4));
        bf16x8 vf = *(const bf16x8*)((const char*)Vs + vbyte);
        oacc[jo] = __builtin_amdgcn_mfma_f32_16x16x32_bf16(pf, vf, oacc[jo], 0, 0, 0);
      }
    }
    __builtin_amdgcn_s_setprio(0);

    if (t > t0) {
      __syncthreads();                           // all waves done reading Ks/Vs
      stage();                                   // refill with tile t-1
      __syncthreads();                           // drains vmcnt: tile t-1 resident
    }
  }

  if constexpr (SP == 1) {
    #pragma unroll
    for (int jo = 0; jo < 8; jo++) {
      #pragma unroll
      for (int rg = 0; rg < 4; rg++) {
        int t = q0 + w * 16 + hi * 4 + rg;
        out[((size_t)b * T_SEQ + t) * HDIM + jo * 16 + lo] = oacc[jo][rg] / lrow[rg];
      }
    }
  } else {
    #pragma unroll
    for (int jo = 0; jo < 8; jo++) {
      #pragma unroll
      for (int rg = 0; rg < 4; rg++) {
        int t = q0 + w * 16 + hi * 4 + rg;
        opart[(((size_t)sp * NB + b) * T_SEQ + t) * HDIM + jo * 16 + lo] = f2bf(oacc[jo][rg]);
      }
    }
    if (lo == 0) {
      #pragma unroll
      for (int rg = 0; rg < 4; rg++) {
        int t = q0 + w * 16 + hi * 4 + rg;
        ml[((size_t)sp * NB + b) * T_SEQ + t] = make_float2(mrow[rg], lrow[rg]);
      }
    }
  }
}

// ---------------- merge of S-split partials (exp2 domain, bf16 partials) ---------------
template <int SP>
__global__ __launch_bounds__(256) void msta_merge_kernel(
    const short* __restrict__ opart, const float2* __restrict__ ml,
    float* __restrict__ out) {
  int id  = blockIdx.x * 256 + threadIdx.x;   // [0, NB*T_SEQ*32)
  int row = id >> 5;                          // b*T_SEQ + t
  int c4  = id & 31;

  float2 v[SP];
  float m = -1e30f;
  #pragma unroll
  for (int sp = 0; sp < SP; sp++) {
    v[sp] = ml[(size_t)sp * (NB * T_SEQ) + row];
    if (v[sp].y > 0.f) m = fmaxf(m, v[sp].x);
  }
  float denom = 0.f;
  float wgt[SP];
  #pragma unroll
  for (int sp = 0; sp < SP; sp++) {
    wgt[sp] = (v[sp].y > 0.f) ? exp2fast(v[sp].x - m) : 0.f;
    denom += wgt[sp] * v[sp].y;
  }
  float4 acc = {0.f, 0.f, 0.f, 0.f};
  #pragma unroll
  for (int sp = 0; sp < SP; sp++) {
    if (wgt[sp] != 0.f) {
      ushort4 o = *(const ushort4*)(opart + ((size_t)sp * (NB * T_SEQ) + row) * HDIM + c4 * 4);
      acc.x += wgt[sp] * bf2f((short)o.x); acc.y += wgt[sp] * bf2f((short)o.y);
      acc.z += wgt[sp] * bf2f((short)o.z); acc.w += wgt[sp] * bf2f((short)o.w);
    }
  }
  float inv = 1.f / denom;
  float4 r = make_float4(acc.x * inv, acc.y * inv, acc.z * inv, acc.w * inv);
  *(float4*)(out + (size_t)row * HDIM + c4 * 4) = r;
}

extern "C" void kernel_launch(void* const* d_in, const int* in_sizes, int n_in,
                              void* d_out, int out_size, void* d_ws, size_t ws_size,
                              hipStream_t stream) {
  (void)in_sizes; (void)n_in; (void)out_size;
  const float* x   = (const float*)d_in[0];
  const float* Wq  = (const float*)d_in[1];
  const float* Wk  = (const float*)d_in[2];
  const float* Wv  = (const float*)d_in[3];
  const float* gfl = (const float*)d_in[4];
  const float* gml = (const float*)d_in[5];
  const float* gsl = (const float*)d_in[6];
  const float* al  = (const float*)d_in[7];
  float* out = (float*)d_out;

  // ws layout (bytes):
  //   bias f32[2048]              @ 0
  //   q    bf16[8*2048*128]       @ 8192
  //   k    bf16                   @ 8192 + 4 MiB
  //   vt   bf16                   @ 8192 + 8 MiB
  //   wt   bf16[packed 786432]    @ 8192 + 12 MiB  (1.5 MiB)
  //   scratch bf16[6.29M] UNION opart bf16[SP][8*2048][128] @ 14680064
  //     (scratch 12.6 MiB is dead after relayout; opart written later by attn)
  //   ml    float2[SP][8*2048]    @ after opart    (SP x 128 KiB)
  char* wsb = (char*)d_ws;
  float*  bias_tab = (float*)wsb;
  short*  qw   = (short*)(wsb + 8192);
  short*  kw   = (short*)(wsb + 8192 + 1 * 4194304);
  short*  vtw  = (short*)(wsb + 8192 + 2 * 4194304);
  short*  wtw  = (short*)(wsb + 8192 + 3 * 4194304);
  short*  scratch = (short*)(wsb + 14680064);
  short*  opart   = (short*)(wsb + 14680064);

  const size_t need8 = 14680064 + 8ull * 4194304 + 8ull * 131072;   // ~49.3 MB (proven)
  const size_t need4 = 14680064 + 4ull * 4194304 + 4ull * 131072;   // ~32.0 MB
  const size_t need1 = 14680064 + 12582912;                         // scratch only

  msta_bias_kernel<<<8, 256, 0, stream>>>(gfl, gml, gsl, al, bias_tab);
  msta_wt_kernel<<<1536, 256, 0, stream>>>(Wq, Wk, Wv, wtw);
  msta_qkv_gemm<<<1024, 256, 0, stream>>>(x, wtw, scratch);
  msta_relayout<<<3072, 256, 0, stream>>>(scratch, qw, kw, vtw);
  (void)need1;

  if (ws_size >= need8) {
    float2* mlp = (float2*)(wsb + 14680064 + 8ull * 4194304);
    msta_attn_kernel<8><<<NB * NQB * 8, 256, 0, stream>>>(qw, kw, vtw, bias_tab,
                                                          nullptr, opart, mlp);
    msta_merge_kernel<8><<<(NB * T_SEQ * 32) / 256, 256, 0, stream>>>(opart, mlp, out);
  } else if (ws_size >= need4) {
    float2* mlp = (float2*)(wsb + 14680064 + 4ull * 4194304);
    msta_attn_kernel<4><<<NB * NQB * 4, 256, 0, stream>>>(qw, kw, vtw, bias_tab,
                                                          nullptr, opart, mlp);
    msta_merge_kernel<4><<<(NB * T_SEQ * 32) / 256, 256, 0, stream>>>(opart, mlp, out);
  } else {
    msta_attn_kernel<1><<<NB * NQB, 256, 0, stream>>>(qw, kw, vtw, bias_tab,
                                                      out, nullptr, nullptr);
  }
}

// Round 17
// 91.150 us; speedup vs baseline: 1.2262x; 1.2262x over previous
//
#include <hip/hip_runtime.h>
#include <hip/hip_bf16.h>
#include <cstdint>

typedef __attribute__((ext_vector_type(8))) short bf16x8;
typedef __attribute__((ext_vector_type(4))) float f32x4;

#define T_SEQ 2048
#define NB    8
#define CDIM  1024
#define HDIM  128
#define NQB   32      // q-blocks of 64 rows per batch

__device__ __forceinline__ float exp2fast(float x) { return __builtin_amdgcn_exp2f(x); }
__device__ __forceinline__ float log2fast(float x) { return __builtin_amdgcn_logf(x); }

__device__ __forceinline__ short f2bf(float f) {
  unsigned u = __float_as_uint(f);
  u += 0x7fff + ((u >> 16) & 1);   // RNE
  return (short)(u >> 16);
}

__device__ __forceinline__ float bf2f(short s) {
  return __uint_as_float(((unsigned)(unsigned short)s) << 16);
}

__device__ __forceinline__ unsigned pk2(float a, float b) {
  return (unsigned)(unsigned short)f2bf(a) | ((unsigned)(unsigned short)f2bf(b) << 16);
}

__device__ __forceinline__ void gload_lds16(const void* gsrc, void* lds_base_uniform) {
  __builtin_amdgcn_global_load_lds(
      (const __attribute__((address_space(1))) unsigned int*)gsrc,
      (__attribute__((address_space(3))) unsigned int*)lds_base_uniform,
      16, 0, 0);
}

// ---------------- bias table (log2 domain): tab[d] = log2(sum_g alpha_g * g^d + 1e-8) --
__global__ void msta_bias_kernel(const float* gfl, const float* gml, const float* gsl,
                                 const float* al, float* tab) {
  int d = blockIdx.x * 256 + threadIdx.x;
  if (d >= T_SEQ) return;
  float gf = 0.30f / (1.f + __expf(-gfl[0])) + 0.60f;
  float gm = 0.15f / (1.f + __expf(-gml[0])) + 0.85f;
  float gs = 0.05f / (1.f + __expf(-gsl[0])) + 0.95f;
  float a0 = al[0], a1 = al[1], a2 = al[2];
  float mx = fmaxf(a0, fmaxf(a1, a2));
  float e0 = __expf(a0 - mx), e1 = __expf(a1 - mx), e2 = __expf(a2 - mx);
  float inv = 1.f / (e0 + e1 + e2);
  float fd = (float)d;
  float mix = e0 * inv * exp2fast(fd * log2fast(gf))
            + e1 * inv * exp2fast(fd * log2fast(gm))
            + e2 * inv * exp2fast(fd * log2fast(gs));
  tab[d] = log2fast(mix + 1e-8f);
}

// ---------------- W pack: MFMA-B-fragment order + bf16; Wq gets H^-0.5*log2(e) ---------
// Packed index: t=k>>6, kk=(k>>5)&1, hi=(k>>3)&3, e=k&7, cf=c>>4, lo=c&15
//   si = (((t*2+kk)*24 + cf)*64 + (hi*16+lo))*8 + e
__global__ void msta_wt_kernel(const float* Wq, const float* Wk, const float* Wv, short* wt) {
  int idx = blockIdx.x * 256 + threadIdx.x;      // [0, 3*128*1024)
  int m = idx >> 17;
  int r = idx & 131071;
  int n = r >> 10;
  int kv = r & 1023;
  const float* W = (m == 0) ? Wq : ((m == 1) ? Wk : Wv);
  float v = W[kv * HDIM + n];
  if (m == 0) v *= 0.08838834764831845f * 1.4426950408889634f;  // H^-0.5 * log2(e)
  int c  = m * 128 + n;
  int t  = kv >> 6, kk = (kv >> 5) & 1, hi = (kv >> 3) & 3, e = kv & 7;
  int cf = c >> 4,  lo = c & 15;
  int si = (((t * 2 + kk) * 24 + cf) * 64 + (hi * 16 + lo)) * 8 + e;
  wt[si] = f2bf(v);
}

// ---------------- QKV: BM=64, ALL 384 cols/block, 8 waves -- traffic-minimal -----------
// L2-traffic model (R16 measurement): all prior variants moved ~300MB L2->CU at MSHR-
// limited ~16-20 B/cy/CU == the invariant 44us. This shape: x read ONCE (64MB f32) +
// W 192KB x 256 blocks (49MB) = 113MB total. Fused LDS-bounce epilogue (no relayout).
__global__ __launch_bounds__(512) void msta_qkv_kernel(
    const float* __restrict__ x, const short* __restrict__ wt,
    short* __restrict__ q, short* __restrict__ k, short* __restrict__ vt) {
  __shared__ short lds[64 * 384];      // 48 KB; k-loop uses first 16 KB as x dbuf

  const int tid  = threadIdx.x;
  const int lane = tid & 63;
  const int w    = tid >> 6;            // 0..7
  const int lo   = lane & 15, hi = lane >> 4;
  const int bid  = blockIdx.x;          // 256 = 8 XCDs * 32
  const int xcd  = bid & 7;
  const int rowblk = bid >> 3;          // 0..31
  const int r0   = xcd * 2048 + rowblk * 64;   // batch b rows live on XCD b

  // x staging: thread g=tid: row=g>>3 (0..63), c8=g&7; 32B f32 NT load -> 16B bf16 LDS
  const int xrow = tid >> 3, xc8 = tid & 7;
  const float* xsrc = x + (size_t)(r0 + xrow) * CDIM + xc8 * 8;
  const int xdst = xrow * 128 + ((xc8 * 16) ^ ((xrow & 7) << 4));   // byte off in buffer

  f32x4 acc[4][3];
  #pragma unroll
  for (int rf = 0; rf < 4; rf++)
    #pragma unroll
    for (int jf = 0; jf < 3; jf++)
      acc[rf][jf] = (f32x4){0.f, 0.f, 0.f, 0.f};

  f32x4 xa, xb;
  auto xload = [&](int t) {
    const f32x4* s = (const f32x4*)(xsrc + t * 64);
    xa = __builtin_nontemporal_load(s);          // x zero-reuse: NT load
    xb = __builtin_nontemporal_load(s + 1);
  };
  auto xwrite = [&](int buf) {
    uint4 u;
    u.x = pk2(xa.x, xa.y); u.y = pk2(xa.z, xa.w);
    u.z = pk2(xb.x, xb.y); u.w = pk2(xb.z, xb.w);
    *(uint4*)((char*)lds + buf * 8192 + xdst) = u;
  };

  // prologue: buffer 0
  xload(0);
  xwrite(0);
  __syncthreads();

  for (int t = 0; t < 16; ++t) {
    const int buf = t & 1;
    if (t < 15) xload(t + 1);              // issue next x reads (hide under compute)

    // 6 B-fragments straight from packed W (1KB coalesced each, L2-resident)
    bf16x8 Bv[2][3];
    #pragma unroll
    for (int kk = 0; kk < 2; kk++)
      #pragma unroll
      for (int jf = 0; jf < 3; jf++) {
        int si = (((t * 2 + kk) * 24 + (w * 3 + jf)) * 64 + lane) * 8;
        Bv[kk][jf] = *(const bf16x8*)(wt + si);
      }

    #pragma unroll
    for (int kk = 0; kk < 2; kk++) {
      #pragma unroll
      for (int rf = 0; rf < 4; rf++) {
        int r = rf * 16 + lo;
        bf16x8 A = *(const bf16x8*)((const char*)lds + buf * 8192 + r * 128 +
                                    ((kk * 64 + hi * 16) ^ ((r & 7) << 4)));
        #pragma unroll
        for (int jf = 0; jf < 3; jf++)
          acc[rf][jf] = __builtin_amdgcn_mfma_f32_16x16x32_bf16(A, Bv[kk][jf], acc[rf][jf], 0, 0, 0);
      }
    }
    if (t < 15) xwrite(buf ^ 1);           // write NEXT buffer (no one reads it now)
    __syncthreads();                       // next buffer staged for all waves
  }

  // ---- epilogue: acc -> LDS [row 64][col 384] bf16, then coalesced stores ----
  #pragma unroll
  for (int rf = 0; rf < 4; rf++) {
    #pragma unroll
    for (int jf = 0; jf < 3; jf++) {
      int c = w * 48 + jf * 16 + lo;
      int row0 = rf * 16 + hi * 4;
      f32x4 a = acc[rf][jf];
      #pragma unroll
      for (int rg = 0; rg < 4; rg++)
        lds[(row0 + rg) * 384 + c] = f2bf(a[rg]);
    }
  }
  __syncthreads();

  // q: cols 0..127; k: cols 128..255 (row-major); vt: cols 256..383 transposed
  #pragma unroll
  for (int p = 0; p < 2; p++) {
    int g = tid + p * 512;                 // 1024 granules
    int row = g >> 4, c16 = g & 15;
    *(bf16x8*)(q + (size_t)(r0 + row) * HDIM + c16 * 8) =
        *(const bf16x8*)(lds + row * 384 + c16 * 8);
    *(bf16x8*)(k + (size_t)(r0 + row) * HDIM + c16 * 8) =
        *(const bf16x8*)(lds + row * 384 + 128 + c16 * 8);
  }
  const int bb = r0 >> 11, tt0 = r0 & 2047;
  #pragma unroll
  for (int p = 0; p < 2; p++) {
    int g = tid + p * 512;                 // 1024 granules: h = g>>3, rowg = g&7
    int h = g >> 3, rowg = g & 7;
    bf16x8 vv;
    #pragma unroll
    for (int i = 0; i < 8; i++)
      vv[i] = lds[(rowg * 8 + i) * 384 + 256 + h];
    *(bf16x8*)(vt + ((size_t)bb * HDIM + h) * T_SEQ + tt0 + rowg * 8) = vv;
  }
}

// ---------------- flash attention: batch==XCD, 4 waves, KT=64, single-buffer -----------
template <int SP>
__global__ __launch_bounds__(256) void msta_attn_kernel(
    const short* __restrict__ q, const short* __restrict__ kg,
    const short* __restrict__ vt, const float* __restrict__ bias_tab,
    float* __restrict__ out, short* __restrict__ opart, float2* __restrict__ ml) {
  __shared__ short Ks[64 * 128];      // [s][h] swizzled, 16 KB
  __shared__ short Vs[128 * 64];      // [h][s] swizzled, 16 KB
  __shared__ short Ps[4][16 * 64];    // per-wave P, swizzled, 8 KB

  const int tid  = threadIdx.x;
  const int lane = tid & 63;
  const int w    = tid >> 6;
  const int lo   = lane & 15, hi = lane >> 4;

  const int idx = blockIdx.x;
  const int b   = idx & 7;                      // batch == XCD (hw: XCD = bid % 8)
  const int r_  = idx >> 3;                     // 0..NQB*SP-1, within-XCD
  const int qb  = (NQB - 1) - r_ / SP;          // LPT: longest q-blocks first
  const int sp  = r_ % SP;
  const int q0  = qb * 64;

  const int nt  = qb + 1;                       // causal tile count for this q-block
  const int csz = (nt + SP - 1) / SP;
  const int t0  = sp * csz;
  const int t1  = (t0 + csz < nt) ? (t0 + csz) : nt;

  if (t0 >= t1) {                               // empty chunk: flag l=0 and exit
    if (SP > 1 && lane < 16) {
      int t = q0 + w * 16 + lane;
      ml[((size_t)sp * NB + b) * T_SEQ + t] = make_float2(-1e30f, 0.f);
    }
    return;
  }

  const short* kb = kg + (size_t)b * T_SEQ * HDIM;
  const short* vb = vt + (size_t)b * HDIM * T_SEQ;

  // Q fragments in registers (16 rows per wave; Wq carries H^-0.5*log2e)
  bf16x8 qf[4];
  const short* qbase = q + ((size_t)b * T_SEQ + q0 + w * 16 + lo) * HDIM;
  #pragma unroll
  for (int ks = 0; ks < 4; ks++)
    qf[ks] = *(const bf16x8*)(qbase + ks * 32 + hi * 8);

  // staging pointers at the LAST tile; decremented per stage() call (descending)
  const int s0i = (t1 - 1) * 64;
  const char* ksrc[4];
  const char* vsrc[4];
  #pragma unroll
  for (int i = 0; i < 4; i++) {
    int G = (w * 4 + i) * 64 + lane;
    { int r = G >> 4, g = G & 15;
      int c = (g & 8) | ((g & 7) ^ (r & 7));
      ksrc[i] = (const char*)(kb + (size_t)(s0i + r) * HDIM) + c * 16; }
    { int r = G >> 3, g = G & 7;
      int c = g ^ (r & 7);
      vsrc[i] = (const char*)(vb + (size_t)r * T_SEQ + s0i) + c * 16; }
  }
  auto stage = [&]() {
    #pragma unroll
    for (int i = 0; i < 4; i++) {
      gload_lds16(ksrc[i], (char*)Ks + (w * 4 + i) * 1024);
      ksrc[i] -= 64 * HDIM * 2;
      gload_lds16(vsrc[i], (char*)Vs + (w * 4 + i) * 1024);
      vsrc[i] -= 128;
    }
  };

  f32x4 oacc[8];
  #pragma unroll
  for (int jo = 0; jo < 8; jo++) oacc[jo] = (f32x4){0.f, 0.f, 0.f, 0.f};
  float mrow[4], lrow[4];
  #pragma unroll
  for (int rg = 0; rg < 4; rg++) { mrow[rg] = -1e30f; lrow[rg] = 0.f; }

  stage();
  __syncthreads();                               // drains vmcnt: tile t1-1 resident

  for (int t = t1 - 1; t >= t0; --t) {
    const int s0 = t * 64;

    // S = Q @ K^T   (16 x 64 per wave), log2 domain
    f32x4 sacc[4];
    #pragma unroll
    for (int jf = 0; jf < 4; jf++) sacc[jf] = (f32x4){0.f, 0.f, 0.f, 0.f};
    __builtin_amdgcn_s_setprio(1);
    #pragma unroll
    for (int ks = 0; ks < 4; ks++) {
      #pragma unroll
      for (int jf = 0; jf < 4; jf++) {
        int s = jf * 16 + lo;
        int byteoff = s * 256 + ((ks * 64 + hi * 16) ^ ((s & 7) << 4));
        bf16x8 kf = *(const bf16x8*)((const char*)Ks + byteoff);
        sacc[jf] = __builtin_amdgcn_mfma_f32_16x16x32_bf16(qf[ks], kf, sacc[jf], 0, 0, 0);
      }
    }
    __builtin_amdgcn_s_setprio(0);

    // bias + causal mask
    float sv[4][4];
    #pragma unroll
    for (int jf = 0; jf < 4; jf++) {
      #pragma unroll
      for (int rg = 0; rg < 4; rg++) {
        int i_ = q0 + w * 16 + hi * 4 + rg;
        int j_ = s0 + jf * 16 + lo;
        int d = i_ - j_;
        sv[jf][rg] = (d >= 0) ? (sacc[jf][rg] + bias_tab[d]) : -1e30f;
      }
    }

    // row max (within 16-lane group); defer-max: skip rescale unless max grew
    float mx[4];
    bool need = false;
    #pragma unroll
    for (int rg = 0; rg < 4; rg++) {
      float v = fmaxf(fmaxf(sv[0][rg], sv[1][rg]), fmaxf(sv[2][rg], sv[3][rg]));
      v = fmaxf(v, __shfl_xor(v, 1));
      v = fmaxf(v, __shfl_xor(v, 2));
      v = fmaxf(v, __shfl_xor(v, 4));
      v = fmaxf(v, __shfl_xor(v, 8));
      mx[rg] = v;
      need |= (v > mrow[rg]);
    }
    if (__any((int)need)) {
      #pragma unroll
      for (int rg = 0; rg < 4; rg++) {
        float mnew = fmaxf(mrow[rg], mx[rg]);
        float sc = exp2fast(mrow[rg] - mnew);
        mrow[rg] = mnew;
        lrow[rg] *= sc;
        #pragma unroll
        for (int jo = 0; jo < 8; jo++) oacc[jo][rg] *= sc;
      }
    }

    // P = exp2(sv - m) -> bf16 into per-wave LDS (A-layout bounce) + row sums
    float psum[4] = {0.f, 0.f, 0.f, 0.f};
    #pragma unroll
    for (int jf = 0; jf < 4; jf++) {
      #pragma unroll
      for (int rg = 0; rg < 4; rg++) {
        float p = exp2fast(sv[jf][rg] - mrow[rg]);
        psum[rg] += p;
        int prow = hi * 4 + rg;
        int pcol = jf * 16 + lo;
        int byteoff = prow * 128 + ((pcol * 2) ^ ((prow & 7) << 4));
        *(short*)((char*)Ps[w] + byteoff) = f2bf(p);
      }
    }
    #pragma unroll
    for (int rg = 0; rg < 4; rg++) {
      float s = psum[rg];
      s += __shfl_xor(s, 1); s += __shfl_xor(s, 2);
      s += __shfl_xor(s, 4); s += __shfl_xor(s, 8);
      lrow[rg] += s;
    }

    // O += P @ V
    __builtin_amdgcn_s_setprio(1);
    #pragma unroll
    for (int ks = 0; ks < 2; ks++) {
      int pbyte = lo * 128 + ((ks * 64 + hi * 16) ^ ((lo & 7) << 4));
      bf16x8 pf = *(const bf16x8*)((const char*)Ps[w] + pbyte);
      #pragma unroll
      for (int jo = 0; jo < 8; jo++) {
        int h = jo * 16 + lo;
        int vbyte = h * 128 + ((ks * 64 + hi * 16) ^ ((h & 7) << 4));
        bf16x8 vf = *(const bf16x8*)((const char*)Vs + vbyte);
        oacc[jo] = __builtin_amdgcn_mfma_f32_16x16x32_bf16(pf, vf, oacc[jo], 0, 0, 0);
      }
    }
    __builtin_amdgcn_s_setprio(0);

    if (t > t0) {
      __syncthreads();                           // all waves done reading Ks/Vs
      stage();                                   // refill with tile t-1
      __syncthreads();                           // drains vmcnt: tile t-1 resident
    }
  }

  if constexpr (SP == 1) {
    #pragma unroll
    for (int jo = 0; jo < 8; jo++) {
      #pragma unroll
      for (int rg = 0; rg < 4; rg++) {
        int t = q0 + w * 16 + hi * 4 + rg;
        out[((size_t)b * T_SEQ + t) * HDIM + jo * 16 + lo] = oacc[jo][rg] / lrow[rg];
      }
    }
  } else {
    #pragma unroll
    for (int jo = 0; jo < 8; jo++) {
      #pragma unroll
      for (int rg = 0; rg < 4; rg++) {
        int t = q0 + w * 16 + hi * 4 + rg;
        opart[(((size_t)sp * NB + b) * T_SEQ + t) * HDIM + jo * 16 + lo] = f2bf(oacc[jo][rg]);
      }
    }
    if (lo == 0) {
      #pragma unroll
      for (int rg = 0; rg < 4; rg++) {
        int t = q0 + w * 16 + hi * 4 + rg;
        ml[((size_t)sp * NB + b) * T_SEQ + t] = make_float2(mrow[rg], lrow[rg]);
      }
    }
  }
}

// ---------------- merge of S-split partials (exp2 domain, bf16 partials) ---------------
template <int SP>
__global__ __launch_bounds__(256) void msta_merge_kernel(
    const short* __restrict__ opart, const float2* __restrict__ ml,
    float* __restrict__ out) {
  int id  = blockIdx.x * 256 + threadIdx.x;   // [0, NB*T_SEQ*32)
  int row = id >> 5;                          // b*T_SEQ + t
  int c4  = id & 31;

  float2 v[SP];
  float m = -1e30f;
  #pragma unroll
  for (int sp = 0; sp < SP; sp++) {
    v[sp] = ml[(size_t)sp * (NB * T_SEQ) + row];
    if (v[sp].y > 0.f) m = fmaxf(m, v[sp].x);
  }
  float denom = 0.f;
  float wgt[SP];
  #pragma unroll
  for (int sp = 0; sp < SP; sp++) {
    wgt[sp] = (v[sp].y > 0.f) ? exp2fast(v[sp].x - m) : 0.f;
    denom += wgt[sp] * v[sp].y;
  }
  float4 acc = {0.f, 0.f, 0.f, 0.f};
  #pragma unroll
  for (int sp = 0; sp < SP; sp++) {
    if (wgt[sp] != 0.f) {
      ushort4 o = *(const ushort4*)(opart + ((size_t)sp * (NB * T_SEQ) + row) * HDIM + c4 * 4);
      acc.x += wgt[sp] * bf2f((short)o.x); acc.y += wgt[sp] * bf2f((short)o.y);
      acc.z += wgt[sp] * bf2f((short)o.z); acc.w += wgt[sp] * bf2f((short)o.w);
    }
  }
  float inv = 1.f / denom;
  float4 r = make_float4(acc.x * inv, acc.y * inv, acc.z * inv, acc.w * inv);
  *(float4*)(out + (size_t)row * HDIM + c4 * 4) = r;
}

extern "C" void kernel_launch(void* const* d_in, const int* in_sizes, int n_in,
                              void* d_out, int out_size, void* d_ws, size_t ws_size,
                              hipStream_t stream) {
  (void)in_sizes; (void)n_in; (void)out_size;
  const float* x   = (const float*)d_in[0];
  const float* Wq  = (const float*)d_in[1];
  const float* Wk  = (const float*)d_in[2];
  const float* Wv  = (const float*)d_in[3];
  const float* gfl = (const float*)d_in[4];
  const float* gml = (const float*)d_in[5];
  const float* gsl = (const float*)d_in[6];
  const float* al  = (const float*)d_in[7];
  float* out = (float*)d_out;

  // ws layout (bytes):
  //   bias f32[2048]              @ 0
  //   q    bf16[8*2048*128]       @ 8192
  //   k    bf16                   @ 8192 + 4 MiB
  //   vt   bf16                   @ 8192 + 8 MiB
  //   wt   bf16[packed 786432]    @ 8192 + 12 MiB  (1.5 MiB)
  //   opart bf16[SP][8*2048][128] @ 14680064       (SP x 4 MiB)
  //   ml    float2[SP][8*2048]    @ after opart    (SP x 128 KiB)
  char* wsb = (char*)d_ws;
  float*  bias_tab = (float*)wsb;
  short*  qw   = (short*)(wsb + 8192);
  short*  kw   = (short*)(wsb + 8192 + 1 * 4194304);
  short*  vtw  = (short*)(wsb + 8192 + 2 * 4194304);
  short*  wtw  = (short*)(wsb + 8192 + 3 * 4194304);
  short*  opart = (short*)(wsb + 14680064);

  const size_t need8 = 14680064 + 8ull * 4194304 + 8ull * 131072;   // ~49.3 MB (proven)
  const size_t need4 = 14680064 + 4ull * 4194304 + 4ull * 131072;   // ~32.0 MB

  msta_bias_kernel<<<8, 256, 0, stream>>>(gfl, gml, gsl, al, bias_tab);
  msta_wt_kernel<<<1536, 256, 0, stream>>>(Wq, Wk, Wv, wtw);
  msta_qkv_kernel<<<256, 512, 0, stream>>>(x, wtw, qw, kw, vtw);

  if (ws_size >= need8) {
    float2* mlp = (float2*)(wsb + 14680064 + 8ull * 4194304);
    msta_attn_kernel<8><<<NB * NQB * 8, 256, 0, stream>>>(qw, kw, vtw, bias_tab,
                                                          nullptr, opart, mlp);
    msta_merge_kernel<8><<<(NB * T_SEQ * 32) / 256, 256, 0, stream>>>(opart, mlp, out);
  } else if (ws_size >= need4) {
    float2* mlp = (float2*)(wsb + 14680064 + 4ull * 4194304);
    msta_attn_kernel<4><<<NB * NQB * 4, 256, 0, stream>>>(qw, kw, vtw, bias_tab,
                                                          nullptr, opart, mlp);
    msta_merge_kernel<4><<<(NB * T_SEQ * 32) / 256, 256, 0, stream>>>(opart, mlp, out);
  } else {
    msta_attn_kernel<1><<<NB * NQB, 256, 0, stream>>>(qw, kw, vtw, bias_tab,
                                                      out, nullptr, nullptr);
  }
}

// Round 18
// 90.014 us; speedup vs baseline: 1.2416x; 1.0126x over previous
//
#include <hip/hip_runtime.h>
#include <hip/hip_bf16.h>
#include <cstdint>

typedef __attribute__((ext_vector_type(8))) short bf16x8;
typedef __attribute__((ext_vector_type(4))) float f32x4;

#define T_SEQ 2048
#define NB    8
#define CDIM  1024
#define HDIM  128
#define NQB   32      // q-blocks of 64 rows per batch

__device__ __forceinline__ float exp2fast(float x) { return __builtin_amdgcn_exp2f(x); }
__device__ __forceinline__ float log2fast(float x) { return __builtin_amdgcn_logf(x); }

__device__ __forceinline__ short f2bf(float f) {
  unsigned u = __float_as_uint(f);
  u += 0x7fff + ((u >> 16) & 1);   // RNE
  return (short)(u >> 16);
}

__device__ __forceinline__ float bf2f(short s) {
  return __uint_as_float(((unsigned)(unsigned short)s) << 16);
}

__device__ __forceinline__ unsigned pk2(float a, float b) {
  return (unsigned)(unsigned short)f2bf(a) | ((unsigned)(unsigned short)f2bf(b) << 16);
}

__device__ __forceinline__ void gload_lds16(const void* gsrc, void* lds_base_uniform) {
  __builtin_amdgcn_global_load_lds(
      (const __attribute__((address_space(1))) unsigned int*)gsrc,
      (__attribute__((address_space(3))) unsigned int*)lds_base_uniform,
      16, 0, 0);
}

// ---------------- bias table (log2 domain): tab[d] = log2(sum_g alpha_g * g^d + 1e-8) --
__global__ void msta_bias_kernel(const float* gfl, const float* gml, const float* gsl,
                                 const float* al, float* tab) {
  int d = blockIdx.x * 256 + threadIdx.x;
  if (d >= T_SEQ) return;
  float gf = 0.30f / (1.f + __expf(-gfl[0])) + 0.60f;
  float gm = 0.15f / (1.f + __expf(-gml[0])) + 0.85f;
  float gs = 0.05f / (1.f + __expf(-gsl[0])) + 0.95f;
  float a0 = al[0], a1 = al[1], a2 = al[2];
  float mx = fmaxf(a0, fmaxf(a1, a2));
  float e0 = __expf(a0 - mx), e1 = __expf(a1 - mx), e2 = __expf(a2 - mx);
  float inv = 1.f / (e0 + e1 + e2);
  float fd = (float)d;
  float mix = e0 * inv * exp2fast(fd * log2fast(gf))
            + e1 * inv * exp2fast(fd * log2fast(gm))
            + e2 * inv * exp2fast(fd * log2fast(gs));
  tab[d] = log2fast(mix + 1e-8f);
}

// ---------------- W transpose + bf16 cast; Wq gets H^-0.5 * log2(e) folded in ----------
__global__ void msta_wt_kernel(const float* Wq, const float* Wk, const float* Wv, short* wt) {
  int idx = blockIdx.x * 256 + threadIdx.x;      // [0, 3*128*1024)
  int m = idx >> 17;
  int r = idx & 131071;
  int n = r >> 10;
  int kk = r & 1023;
  const float* W = (m == 0) ? Wq : ((m == 1) ? Wk : Wv);
  float v = W[kk * HDIM + n];
  if (m == 0) v *= 0.08838834764831845f * 1.4426950408889634f;  // H^-0.5 * log2(e)
  wt[idx] = f2bf(v);
}

// ---------------- QKV: split-m XCD-grouped, SINGLE-buffer 32KB (R12 config, 84.6us) ----
__global__ __launch_bounds__(256) void msta_qkv_kernel(
    const float* __restrict__ x, const short* __restrict__ wt,
    short* __restrict__ q, short* __restrict__ k, short* __restrict__ vt) {
  __shared__ float xs[64 * 64];      // [row][k] f32, granule-swizzled, 16 KB
  __shared__ short wsm[128 * 64];    // [n][k] bf16, swizzled, 16 KB

  const int tid  = threadIdx.x;
  const int lane = tid & 63;
  const int w    = tid >> 6;
  const int rh   = w >> 1, ch = w & 1;
  const int lo   = lane & 15, hi = lane >> 4;
  const int bid  = blockIdx.x;          // 768 = 8 XCDs * 96
  const int xcd  = bid & 7;
  const int j    = bid >> 3;            // 0..95
  const int m    = j % 3;               // m-triple co-resident on one XCD
  const int r0   = (xcd * 32 + j / 3) * 64;   // batch b rows live on XCD b

  // staging sources (pre-swizzled), advanced per k-step
  const char* xsrc[4];
  const char* wsrc[4];
  #pragma unroll
  for (int i = 0; i < 4; i++) {
    int G = (w * 4 + i) * 64 + lane;
    { int r = G >> 4, g = G & 15;              // x: 64 rows x 16 granules (f32)
      int c = g ^ (r & 15);
      xsrc[i] = (const char*)(x + (size_t)(r0 + r) * CDIM) + c * 16; }
    { int n = G >> 3, g = G & 7;               // W: 128 n-rows x 8 granules (bf16)
      int c = g ^ (n & 7);
      wsrc[i] = (const char*)(wt + ((size_t)m * 128 + n) * CDIM) + c * 16; }
  }

  f32x4 acc[2][4];
  #pragma unroll
  for (int f = 0; f < 2; f++)
    #pragma unroll
    for (int jf = 0; jf < 4; jf++)
      acc[f][jf] = (f32x4){0.f, 0.f, 0.f, 0.f};

  for (int t = 0; t < 16; ++t) {
    #pragma unroll
    for (int i = 0; i < 4; i++) {
      gload_lds16(xsrc[i], (char*)xs + (w * 4 + i) * 1024);
      xsrc[i] += 256;                          // 64 f32
      gload_lds16(wsrc[i], (char*)wsm + (w * 4 + i) * 1024);
      wsrc[i] += 128;                          // 64 bf16
    }
    __syncthreads();                           // drains vmcnt: buffers resident

    #pragma unroll
    for (int kk = 0; kk < 2; kk++) {
      bf16x8 A[2];
      #pragma unroll
      for (int f = 0; f < 2; f++) {
        int r = rh * 32 + f * 16 + lo;
        int g0 = kk * 8 + hi * 2;
        int sw = r & 15;
        const char* base = (const char*)xs + r * 256;
        float4 a0 = *(const float4*)(base + (((g0)     ^ sw) << 4));
        float4 a1 = *(const float4*)(base + (((g0 + 1) ^ sw) << 4));
        uint4 u;
        u.x = pk2(a0.x, a0.y); u.y = pk2(a0.z, a0.w);
        u.z = pk2(a1.x, a1.y); u.w = pk2(a1.z, a1.w);
        A[f] = *(bf16x8*)&u;
      }
      #pragma unroll
      for (int jf = 0; jf < 4; jf++) {
        int n = ch * 64 + jf * 16 + lo;
        int byteoff = n * 128 + ((kk * 64 + hi * 16) ^ ((n & 7) << 4));
        bf16x8 Bv = *(const bf16x8*)((const char*)wsm + byteoff);
        acc[0][jf] = __builtin_amdgcn_mfma_f32_16x16x32_bf16(A[0], Bv, acc[0][jf], 0, 0, 0);
        acc[1][jf] = __builtin_amdgcn_mfma_f32_16x16x32_bf16(A[1], Bv, acc[1][jf], 0, 0, 0);
      }
    }
    __syncthreads();                           // all reads done; next stage may overwrite
  }

  // ---- epilogue: bounce 64x128 bf16 output tile through LDS, store coalesced b128 ----
  short* es = (short*)xs;                      // 16 KB, reused after final sync
  if (m == 2) {
    #pragma unroll
    for (int f = 0; f < 2; f++) {
      #pragma unroll
      for (int jf = 0; jf < 4; jf++) {
        int col  = ch * 64 + jf * 16 + lo;
        int trow = rh * 32 + f * 16 + hi * 4;
        f32x4 a = acc[f][jf];
        uint2 pr;
        pr.x = pk2(a[0], a[1]);
        pr.y = pk2(a[2], a[3]);
        int byteoff = col * 128 + ((trow * 2) ^ ((col & 7) << 4));
        *(uint2*)((char*)es + byteoff) = pr;
      }
    }
    __syncthreads();
    const int bb = r0 >> 11, tt0 = r0 & 2047;
    short* vbase = vt + (size_t)bb * HDIM * T_SEQ + tt0;
    #pragma unroll
    for (int p = 0; p < 4; p++) {
      int col = (tid >> 3) + p * 32;
      int t8  = tid & 7;
      int byteoff = col * 128 + ((t8 * 16) ^ ((col & 7) << 4));
      *(bf16x8*)(vbase + (size_t)col * T_SEQ + t8 * 8) =
          *(const bf16x8*)((const char*)es + byteoff);
    }
  } else {
    short* dst = (m == 0) ? q : k;
    #pragma unroll
    for (int f = 0; f < 2; f++) {
      #pragma unroll
      for (int jf = 0; jf < 4; jf++) {
        int col   = ch * 64 + jf * 16 + lo;
        int trow0 = rh * 32 + f * 16 + hi * 4;
        f32x4 a = acc[f][jf];
        #pragma unroll
        for (int rg = 0; rg < 4; rg++)
          es[(trow0 + rg) * 128 + col] = f2bf(a[rg]);
      }
    }
    __syncthreads();
    #pragma unroll
    for (int p = 0; p < 4; p++) {
      int row = (tid >> 4) + p * 16;
      int c16 = tid & 15;
      *(bf16x8*)(dst + (size_t)(r0 + row) * HDIM + c16 * 8) =
          *(const bf16x8*)(es + row * 128 + c16 * 8);
    }
  }
}

// ---------------- flash attention: batch==XCD, 4 waves, KT=32, 20KB LDS ----------------
// KT 64->32: LDS 40->20KB => 6 blocks/CU (24 waves) vs 4 (16); per-tile latency chain
// halves (8 exp2, 8 MFMA/phase). More independent chains hide staging+softmax latency.
template <int SP>
__global__ __launch_bounds__(256) void msta_attn_kernel(
    const short* __restrict__ q, const short* __restrict__ kg,
    const short* __restrict__ vt, const float* __restrict__ bias_tab,
    float* __restrict__ out, short* __restrict__ opart, float2* __restrict__ ml) {
  __shared__ short Ks[32 * 128];      // [s][h] swizzled, 8 KB
  __shared__ short Vs[128 * 32];      // [h][s] swizzled, 8 KB
  __shared__ short Ps[4][16 * 32];    // per-wave P, swizzled, 4 KB

  const int tid  = threadIdx.x;
  const int lane = tid & 63;
  const int w    = tid >> 6;
  const int lo   = lane & 15, hi = lane >> 4;

  const int idx = blockIdx.x;
  const int b   = idx & 7;                      // batch == XCD (hw: XCD = bid % 8)
  const int r_  = idx >> 3;                     // 0..NQB*SP-1, within-XCD
  const int qb  = (NQB - 1) - r_ / SP;          // LPT: longest q-blocks first
  const int sp  = r_ % SP;
  const int q0  = qb * 64;

  const int nt  = 2 * (qb + 1);                 // causal KT=32 tile count
  const int csz = (nt + SP - 1) / SP;
  const int t0  = sp * csz;
  const int t1  = (t0 + csz < nt) ? (t0 + csz) : nt;

  if (t0 >= t1) {                               // empty chunk: flag l=0 and exit
    if (SP > 1 && lane < 16) {
      int t = q0 + w * 16 + lane;
      ml[((size_t)sp * NB + b) * T_SEQ + t] = make_float2(-1e30f, 0.f);
    }
    return;
  }

  const short* kb = kg + (size_t)b * T_SEQ * HDIM;
  const short* vb = vt + (size_t)b * HDIM * T_SEQ;

  // Q fragments in registers (16 rows per wave; Wq carries H^-0.5*log2e)
  bf16x8 qf[4];
  const short* qbase = q + ((size_t)b * T_SEQ + q0 + w * 16 + lo) * HDIM;
  #pragma unroll
  for (int ks = 0; ks < 4; ks++)
    qf[ks] = *(const bf16x8*)(qbase + ks * 32 + hi * 8);

  // staging pointers at the LAST tile; decremented per stage() (descending)
  const int s0i = (t1 - 1) * 32;
  const char* ksrc[2];
  const char* vsrc[2];
  #pragma unroll
  for (int i = 0; i < 2; i++) {
    int G = (w * 2 + i) * 64 + lane;            // 0..511
    { int r = G >> 4, g = G & 15;               // K: 32 rows x 16 granules
      int c = (g & 8) | ((g & 7) ^ (r & 7));
      ksrc[i] = (const char*)(kb + (size_t)(s0i + r) * HDIM) + c * 16; }
    { int r = G >> 2, g = G & 3;                // Vt: 128 rows x 4 granules
      int c = g ^ (r & 3);
      vsrc[i] = (const char*)(vb + (size_t)r * T_SEQ + s0i) + c * 16; }
  }
  auto stage = [&]() {
    #pragma unroll
    for (int i = 0; i < 2; i++) {
      gload_lds16(ksrc[i], (char*)Ks + (w * 2 + i) * 1024);
      ksrc[i] -= 32 * HDIM * 2;                 // back one 32-tile of K rows
      gload_lds16(vsrc[i], (char*)Vs + (w * 2 + i) * 1024);
      vsrc[i] -= 64;                            // back 32 bf16 cols
    }
  };

  f32x4 oacc[8];
  #pragma unroll
  for (int jo = 0; jo < 8; jo++) oacc[jo] = (f32x4){0.f, 0.f, 0.f, 0.f};
  float mrow[4], lrow[4];
  #pragma unroll
  for (int rg = 0; rg < 4; rg++) { mrow[rg] = -1e30f; lrow[rg] = 0.f; }

  stage();
  __syncthreads();                               // tile t1-1 resident

  for (int t = t1 - 1; t >= t0; --t) {
    const int s0 = t * 32;

    // S = Q @ K^T   (16 x 32 per wave), log2 domain
    f32x4 sacc[2];
    #pragma unroll
    for (int jf = 0; jf < 2; jf++) sacc[jf] = (f32x4){0.f, 0.f, 0.f, 0.f};
    __builtin_amdgcn_s_setprio(1);
    #pragma unroll
    for (int ks = 0; ks < 4; ks++) {
      #pragma unroll
      for (int jf = 0; jf < 2; jf++) {
        int s = jf * 16 + lo;
        int byteoff = s * 256 + ((ks * 64 + hi * 16) ^ ((s & 7) << 4));
        bf16x8 kf = *(const bf16x8*)((const char*)Ks + byteoff);
        sacc[jf] = __builtin_amdgcn_mfma_f32_16x16x32_bf16(qf[ks], kf, sacc[jf], 0, 0, 0);
      }
    }
    __builtin_amdgcn_s_setprio(0);

    // bias + causal mask
    float sv[2][4];
    #pragma unroll
    for (int jf = 0; jf < 2; jf++) {
      #pragma unroll
      for (int rg = 0; rg < 4; rg++) {
        int i_ = q0 + w * 16 + hi * 4 + rg;
        int j_ = s0 + jf * 16 + lo;
        int d = i_ - j_;
        sv[jf][rg] = (d >= 0) ? (sacc[jf][rg] + bias_tab[d]) : -1e30f;
      }
    }

    // row max (within 16-lane group); defer-max: skip rescale unless max grew
    float mx[4];
    bool need = false;
    #pragma unroll
    for (int rg = 0; rg < 4; rg++) {
      float v = fmaxf(sv[0][rg], sv[1][rg]);
      v = fmaxf(v, __shfl_xor(v, 1));
      v = fmaxf(v, __shfl_xor(v, 2));
      v = fmaxf(v, __shfl_xor(v, 4));
      v = fmaxf(v, __shfl_xor(v, 8));
      mx[rg] = v;
      need |= (v > mrow[rg]);
    }
    if (__any((int)need)) {
      #pragma unroll
      for (int rg = 0; rg < 4; rg++) {
        float mnew = fmaxf(mrow[rg], mx[rg]);
        float sc = exp2fast(mrow[rg] - mnew);
        mrow[rg] = mnew;
        lrow[rg] *= sc;
        #pragma unroll
        for (int jo = 0; jo < 8; jo++) oacc[jo][rg] *= sc;
      }
    }

    // P = exp2(sv - m) -> bf16 into per-wave LDS (A-layout bounce) + row sums
    float psum[4] = {0.f, 0.f, 0.f, 0.f};
    #pragma unroll
    for (int jf = 0; jf < 2; jf++) {
      #pragma unroll
      for (int rg = 0; rg < 4; rg++) {
        float p = exp2fast(sv[jf][rg] - mrow[rg]);
        psum[rg] += p;
        int prow = hi * 4 + rg;
        int pcol = jf * 16 + lo;
        int byteoff = prow * 64 + ((pcol * 2) ^ ((prow & 3) << 4));
        *(short*)((char*)Ps[w] + byteoff) = f2bf(p);
      }
    }
    #pragma unroll
    for (int rg = 0; rg < 4; rg++) {
      float s = psum[rg];
      s += __shfl_xor(s, 1); s += __shfl_xor(s, 2);
      s += __shfl_xor(s, 4); s += __shfl_xor(s, 8);
      lrow[rg] += s;
    }

    // O += P @ V  (single K=32 step)
    __builtin_amdgcn_s_setprio(1);
    {
      int pbyte = lo * 64 + ((hi * 16) ^ ((lo & 3) << 4));
      bf16x8 pf = *(const bf16x8*)((const char*)Ps[w] + pbyte);
      #pragma unroll
      for (int jo = 0; jo < 8; jo++) {
        int h = jo * 16 + lo;
        int vbyte = h * 64 + ((hi * 16) ^ ((h & 3) << 4));
        bf16x8 vf = *(const bf16x8*)((const char*)Vs + vbyte);
        oacc[jo] = __builtin_amdgcn_mfma_f32_16x16x32_bf16(pf, vf, oacc[jo], 0, 0, 0);
      }
    }
    __builtin_amdgcn_s_setprio(0);

    if (t > t0) {
      __syncthreads();                           // all waves done reading Ks/Vs
      stage();                                   // refill with tile t-1
      __syncthreads();                           // tile t-1 resident
    }
  }

  if constexpr (SP == 1) {
    #pragma unroll
    for (int jo = 0; jo < 8; jo++) {
      #pragma unroll
      for (int rg = 0; rg < 4; rg++) {
        int t = q0 + w * 16 + hi * 4 + rg;
        out[((size_t)b * T_SEQ + t) * HDIM + jo * 16 + lo] = oacc[jo][rg] / lrow[rg];
      }
    }
  } else {
    #pragma unroll
    for (int jo = 0; jo < 8; jo++) {
      #pragma unroll
      for (int rg = 0; rg < 4; rg++) {
        int t = q0 + w * 16 + hi * 4 + rg;
        opart[(((size_t)sp * NB + b) * T_SEQ + t) * HDIM + jo * 16 + lo] = f2bf(oacc[jo][rg]);
      }
    }
    if (lo == 0) {
      #pragma unroll
      for (int rg = 0; rg < 4; rg++) {
        int t = q0 + w * 16 + hi * 4 + rg;
        ml[((size_t)sp * NB + b) * T_SEQ + t] = make_float2(mrow[rg], lrow[rg]);
      }
    }
  }
}

// ---------------- merge of S-split partials (exp2 domain, bf16 partials) ---------------
template <int SP>
__global__ __launch_bounds__(256) void msta_merge_kernel(
    const short* __restrict__ opart, const float2* __restrict__ ml,
    float* __restrict__ out) {
  int id  = blockIdx.x * 256 + threadIdx.x;   // [0, NB*T_SEQ*32)
  int row = id >> 5;                          // b*T_SEQ + t
  int c4  = id & 31;

  float2 v[SP];
  float m = -1e30f;
  #pragma unroll
  for (int sp = 0; sp < SP; sp++) {
    v[sp] = ml[(size_t)sp * (NB * T_SEQ) + row];
    if (v[sp].y > 0.f) m = fmaxf(m, v[sp].x);
  }
  float denom = 0.f;
  float wgt[SP];
  #pragma unroll
  for (int sp = 0; sp < SP; sp++) {
    wgt[sp] = (v[sp].y > 0.f) ? exp2fast(v[sp].x - m) : 0.f;
    denom += wgt[sp] * v[sp].y;
  }
  float4 acc = {0.f, 0.f, 0.f, 0.f};
  #pragma unroll
  for (int sp = 0; sp < SP; sp++) {
    if (wgt[sp] != 0.f) {
      ushort4 o = *(const ushort4*)(opart + ((size_t)sp * (NB * T_SEQ) + row) * HDIM + c4 * 4);
      acc.x += wgt[sp] * bf2f((short)o.x); acc.y += wgt[sp] * bf2f((short)o.y);
      acc.z += wgt[sp] * bf2f((short)o.z); acc.w += wgt[sp] * bf2f((short)o.w);
    }
  }
  float inv = 1.f / denom;
  float4 r = make_float4(acc.x * inv, acc.y * inv, acc.z * inv, acc.w * inv);
  *(float4*)(out + (size_t)row * HDIM + c4 * 4) = r;
}

extern "C" void kernel_launch(void* const* d_in, const int* in_sizes, int n_in,
                              void* d_out, int out_size, void* d_ws, size_t ws_size,
                              hipStream_t stream) {
  (void)in_sizes; (void)n_in; (void)out_size;
  const float* x   = (const float*)d_in[0];
  const float* Wq  = (const float*)d_in[1];
  const float* Wk  = (const float*)d_in[2];
  const float* Wv  = (const float*)d_in[3];
  const float* gfl = (const float*)d_in[4];
  const float* gml = (const float*)d_in[5];
  const float* gsl = (const float*)d_in[6];
  const float* al  = (const float*)d_in[7];
  float* out = (float*)d_out;

  // ws layout (bytes):
  //   bias f32[2048]              @ 0
  //   q    bf16[8*2048*128]       @ 8192
  //   k    bf16                   @ 8192 + 4 MiB
  //   vt   bf16                   @ 8192 + 8 MiB
  //   wt   bf16[3*128*1024]       @ 8192 + 12 MiB  (768 KiB)
  //   opart bf16[SP][8*2048][128] @ 13639680       (SP x 4 MiB)
  //   ml    float2[SP][8*2048]    @ after opart    (SP x 128 KiB)
  char* wsb = (char*)d_ws;
  float*  bias_tab = (float*)wsb;
  short*  qw   = (short*)(wsb + 8192);
  short*  kw   = (short*)(wsb + 8192 + 1 * 4194304);
  short*  vtw  = (short*)(wsb + 8192 + 2 * 4194304);
  short*  wtw  = (short*)(wsb + 8192 + 3 * 4194304);
  short*  opart = (short*)(wsb + 13639680);

  const size_t need8 = 13639680 + 8ull * 4194304 + 8ull * 131072;   // ~48.2 MB (proven)
  const size_t need4 = 13639680 + 4ull * 4194304 + 4ull * 131072;   // ~31.0 MB

  msta_bias_kernel<<<8, 256, 0, stream>>>(gfl, gml, gsl, al, bias_tab);
  msta_wt_kernel<<<1536, 256, 0, stream>>>(Wq, Wk, Wv, wtw);
  msta_qkv_kernel<<<768, 256, 0, stream>>>(x, wtw, qw, kw, vtw);

  if (ws_size >= need8) {
    float2* mlp = (float2*)(wsb + 13639680 + 8ull * 4194304);
    msta_attn_kernel<8><<<NB * NQB * 8, 256, 0, stream>>>(qw, kw, vtw, bias_tab,
                                                          nullptr, opart, mlp);
    msta_merge_kernel<8><<<(NB * T_SEQ * 32) / 256, 256, 0, stream>>>(opart, mlp, out);
  } else if (ws_size >= need4) {
    float2* mlp = (float2*)(wsb + 13639680 + 4ull * 4194304);
    msta_attn_kernel<4><<<NB * NQB * 4, 256, 0, stream>>>(qw, kw, vtw, bias_tab,
                                                          nullptr, opart, mlp);
    msta_merge_kernel<4><<<(NB * T_SEQ * 32) / 256, 256, 0, stream>>>(opart, mlp, out);
  } else {
    msta_attn_kernel<1><<<NB * NQB, 256, 0, stream>>>(qw, kw, vtw, bias_tab,
                                                      out, nullptr, nullptr);
  }
}

// Round 19
// 81.628 us; speedup vs baseline: 1.3692x; 1.1027x over previous
//
#include <hip/hip_runtime.h>
#include <hip/hip_bf16.h>
#include <cstdint>

typedef __attribute__((ext_vector_type(8))) short bf16x8;
typedef __attribute__((ext_vector_type(4))) float f32x4;

#define T_SEQ 2048
#define NB    8
#define CDIM  1024
#define HDIM  128
#define NQB   32      // q-blocks of 64 rows per batch

__device__ __forceinline__ float exp2fast(float x) { return __builtin_amdgcn_exp2f(x); }
__device__ __forceinline__ float log2fast(float x) { return __builtin_amdgcn_logf(x); }

__device__ __forceinline__ short f2bf(float f) {
  unsigned u = __float_as_uint(f);
  u += 0x7fff + ((u >> 16) & 1);   // RNE
  return (short)(u >> 16);
}

__device__ __forceinline__ float bf2f(short s) {
  return __uint_as_float(((unsigned)(unsigned short)s) << 16);
}

__device__ __forceinline__ unsigned pk2(float a, float b) {
  return (unsigned)(unsigned short)f2bf(a) | ((unsigned)(unsigned short)f2bf(b) << 16);
}

__device__ __forceinline__ void gload_lds16(const void* gsrc, void* lds_base_uniform) {
  __builtin_amdgcn_global_load_lds(
      (const __attribute__((address_space(1))) unsigned int*)gsrc,
      (__attribute__((address_space(3))) unsigned int*)lds_base_uniform,
      16, 0, 0);
}

// ---------------- bias table (log2 domain): tab[d] = log2(sum_g alpha_g * g^d + 1e-8) --
__global__ void msta_bias_kernel(const float* gfl, const float* gml, const float* gsl,
                                 const float* al, float* tab) {
  int d = blockIdx.x * 256 + threadIdx.x;
  if (d >= T_SEQ) return;
  float gf = 0.30f / (1.f + __expf(-gfl[0])) + 0.60f;
  float gm = 0.15f / (1.f + __expf(-gml[0])) + 0.85f;
  float gs = 0.05f / (1.f + __expf(-gsl[0])) + 0.95f;
  float a0 = al[0], a1 = al[1], a2 = al[2];
  float mx = fmaxf(a0, fmaxf(a1, a2));
  float e0 = __expf(a0 - mx), e1 = __expf(a1 - mx), e2 = __expf(a2 - mx);
  float inv = 1.f / (e0 + e1 + e2);
  float fd = (float)d;
  float mix = e0 * inv * exp2fast(fd * log2fast(gf))
            + e1 * inv * exp2fast(fd * log2fast(gm))
            + e2 * inv * exp2fast(fd * log2fast(gs));
  tab[d] = log2fast(mix + 1e-8f);
}

// ---------------- W transpose + bf16 cast; Wq gets H^-0.5 * log2(e) folded in ----------
__global__ void msta_wt_kernel(const float* Wq, const float* Wk, const float* Wv, short* wt) {
  int idx = blockIdx.x * 256 + threadIdx.x;      // [0, 3*128*1024)
  int m = idx >> 17;
  int r = idx & 131071;
  int n = r >> 10;
  int kk = r & 1023;
  const float* W = (m == 0) ? Wq : ((m == 1) ? Wk : Wv);
  float v = W[kk * HDIM + n];
  if (m == 0) v *= 0.08838834764831845f * 1.4426950408889634f;  // H^-0.5 * log2(e)
  wt[idx] = f2bf(v);
}

// ---------------- QKV: split-m XCD-grouped, SINGLE-buffer 32KB (R12 config, proven) ----
__global__ __launch_bounds__(256) void msta_qkv_kernel(
    const float* __restrict__ x, const short* __restrict__ wt,
    short* __restrict__ q, short* __restrict__ k, short* __restrict__ vt) {
  __shared__ float xs[64 * 64];      // [row][k] f32, granule-swizzled, 16 KB
  __shared__ short wsm[128 * 64];    // [n][k] bf16, swizzled, 16 KB

  const int tid  = threadIdx.x;
  const int lane = tid & 63;
  const int w    = tid >> 6;
  const int rh   = w >> 1, ch = w & 1;
  const int lo   = lane & 15, hi = lane >> 4;
  const int bid  = blockIdx.x;          // 768 = 8 XCDs * 96
  const int xcd  = bid & 7;
  const int j    = bid >> 3;            // 0..95
  const int m    = j % 3;               // m-triple co-resident on one XCD
  const int r0   = (xcd * 32 + j / 3) * 64;   // batch b rows live on XCD b

  // staging sources (pre-swizzled), advanced per k-step
  const char* xsrc[4];
  const char* wsrc[4];
  #pragma unroll
  for (int i = 0; i < 4; i++) {
    int G = (w * 4 + i) * 64 + lane;
    { int r = G >> 4, g = G & 15;              // x: 64 rows x 16 granules (f32)
      int c = g ^ (r & 15);
      xsrc[i] = (const char*)(x + (size_t)(r0 + r) * CDIM) + c * 16; }
    { int n = G >> 3, g = G & 7;               // W: 128 n-rows x 8 granules (bf16)
      int c = g ^ (n & 7);
      wsrc[i] = (const char*)(wt + ((size_t)m * 128 + n) * CDIM) + c * 16; }
  }

  f32x4 acc[2][4];
  #pragma unroll
  for (int f = 0; f < 2; f++)
    #pragma unroll
    for (int jf = 0; jf < 4; jf++)
      acc[f][jf] = (f32x4){0.f, 0.f, 0.f, 0.f};

  for (int t = 0; t < 16; ++t) {
    #pragma unroll
    for (int i = 0; i < 4; i++) {
      gload_lds16(xsrc[i], (char*)xs + (w * 4 + i) * 1024);
      xsrc[i] += 256;                          // 64 f32
      gload_lds16(wsrc[i], (char*)wsm + (w * 4 + i) * 1024);
      wsrc[i] += 128;                          // 64 bf16
    }
    __syncthreads();                           // drains vmcnt: buffers resident

    #pragma unroll
    for (int kk = 0; kk < 2; kk++) {
      bf16x8 A[2];
      #pragma unroll
      for (int f = 0; f < 2; f++) {
        int r = rh * 32 + f * 16 + lo;
        int g0 = kk * 8 + hi * 2;
        int sw = r & 15;
        const char* base = (const char*)xs + r * 256;
        float4 a0 = *(const float4*)(base + (((g0)     ^ sw) << 4));
        float4 a1 = *(const float4*)(base + (((g0 + 1) ^ sw) << 4));
        uint4 u;
        u.x = pk2(a0.x, a0.y); u.y = pk2(a0.z, a0.w);
        u.z = pk2(a1.x, a1.y); u.w = pk2(a1.z, a1.w);
        A[f] = *(bf16x8*)&u;
      }
      #pragma unroll
      for (int jf = 0; jf < 4; jf++) {
        int n = ch * 64 + jf * 16 + lo;
        int byteoff = n * 128 + ((kk * 64 + hi * 16) ^ ((n & 7) << 4));
        bf16x8 Bv = *(const bf16x8*)((const char*)wsm + byteoff);
        acc[0][jf] = __builtin_amdgcn_mfma_f32_16x16x32_bf16(A[0], Bv, acc[0][jf], 0, 0, 0);
        acc[1][jf] = __builtin_amdgcn_mfma_f32_16x16x32_bf16(A[1], Bv, acc[1][jf], 0, 0, 0);
      }
    }
    __syncthreads();                           // all reads done; next stage may overwrite
  }

  // ---- epilogue: bounce 64x128 bf16 output tile through LDS, store coalesced b128 ----
  short* es = (short*)xs;                      // 16 KB, reused after final sync
  if (m == 2) {
    #pragma unroll
    for (int f = 0; f < 2; f++) {
      #pragma unroll
      for (int jf = 0; jf < 4; jf++) {
        int col  = ch * 64 + jf * 16 + lo;
        int trow = rh * 32 + f * 16 + hi * 4;
        f32x4 a = acc[f][jf];
        uint2 pr;
        pr.x = pk2(a[0], a[1]);
        pr.y = pk2(a[2], a[3]);
        int byteoff = col * 128 + ((trow * 2) ^ ((col & 7) << 4));
        *(uint2*)((char*)es + byteoff) = pr;
      }
    }
    __syncthreads();
    const int bb = r0 >> 11, tt0 = r0 & 2047;
    short* vbase = vt + (size_t)bb * HDIM * T_SEQ + tt0;
    #pragma unroll
    for (int p = 0; p < 4; p++) {
      int col = (tid >> 3) + p * 32;
      int t8  = tid & 7;
      int byteoff = col * 128 + ((t8 * 16) ^ ((col & 7) << 4));
      *(bf16x8*)(vbase + (size_t)col * T_SEQ + t8 * 8) =
          *(const bf16x8*)((const char*)es + byteoff);
    }
  } else {
    short* dst = (m == 0) ? q : k;
    #pragma unroll
    for (int f = 0; f < 2; f++) {
      #pragma unroll
      for (int jf = 0; jf < 4; jf++) {
        int col   = ch * 64 + jf * 16 + lo;
        int trow0 = rh * 32 + f * 16 + hi * 4;
        f32x4 a = acc[f][jf];
        #pragma unroll
        for (int rg = 0; rg < 4; rg++)
          es[(trow0 + rg) * 128 + col] = f2bf(a[rg]);
      }
    }
    __syncthreads();
    #pragma unroll
    for (int p = 0; p < 4; p++) {
      int row = (tid >> 4) + p * 16;
      int c16 = tid & 15;
      *(bf16x8*)(dst + (size_t)(r0 + row) * HDIM + c16 * 8) =
          *(const bf16x8*)(es + row * 128 + c16 * 8);
    }
  }
}

// ---------------- flash attention: batch==XCD, 4 waves, KT=64, fixed-m softmax ---------
// Descending tiles: row max computed ONCE on the first (diagonal-most) tile, never
// rescaled (exact; merge renormalizes; P bounded ~2^15 -> fp32/bf16 safe).
// lrow accumulated via ones-MFMA (every output col = row sum) -- no psum shuffles.
template <int SP>
__global__ __launch_bounds__(256) void msta_attn_kernel(
    const short* __restrict__ q, const short* __restrict__ kg,
    const short* __restrict__ vt, const float* __restrict__ bias_tab,
    float* __restrict__ out, short* __restrict__ opart, float2* __restrict__ ml) {
  __shared__ short Ks[64 * 128];      // [s][h] swizzled, 16 KB
  __shared__ short Vs[128 * 64];      // [h][s] swizzled, 16 KB
  __shared__ short Ps[4][16 * 64];    // per-wave P, swizzled, 8 KB

  const int tid  = threadIdx.x;
  const int lane = tid & 63;
  const int w    = tid >> 6;
  const int lo   = lane & 15, hi = lane >> 4;

  const int idx = blockIdx.x;
  const int b   = idx & 7;                      // batch == XCD (hw: XCD = bid % 8)
  const int r_  = idx >> 3;                     // 0..NQB*SP-1, within-XCD
  const int qb  = (NQB - 1) - r_ / SP;          // LPT: longest q-blocks first
  const int sp  = r_ % SP;
  const int q0  = qb * 64;

  const int nt  = qb + 1;                       // causal tile count for this q-block
  const int csz = (nt + SP - 1) / SP;
  const int t0  = sp * csz;
  const int t1  = (t0 + csz < nt) ? (t0 + csz) : nt;

  if (t0 >= t1) {                               // empty chunk: flag l=0 and exit
    if (SP > 1 && lane < 16) {
      int t = q0 + w * 16 + lane;
      ml[((size_t)sp * NB + b) * T_SEQ + t] = make_float2(-1e30f, 0.f);
    }
    return;
  }

  const short* kb = kg + (size_t)b * T_SEQ * HDIM;
  const short* vb = vt + (size_t)b * HDIM * T_SEQ;

  // Q fragments in registers (16 rows per wave; Wq carries H^-0.5*log2e)
  bf16x8 qf[4];
  const short* qbase = q + ((size_t)b * T_SEQ + q0 + w * 16 + lo) * HDIM;
  #pragma unroll
  for (int ks = 0; ks < 4; ks++)
    qf[ks] = *(const bf16x8*)(qbase + ks * 32 + hi * 8);

  // all-ones bf16 fragment (1.0 = 0x3F80): B of ones-MFMA -> D[r][c] = row sum, all c
  bf16x8 ones;
  #pragma unroll
  for (int i = 0; i < 8; i++) ones[i] = (short)0x3F80;

  // staging pointers at the LAST tile; decremented per stage() call (descending)
  const int s0i = (t1 - 1) * 64;
  const char* ksrc[4];
  const char* vsrc[4];
  #pragma unroll
  for (int i = 0; i < 4; i++) {
    int G = (w * 4 + i) * 64 + lane;
    { int r = G >> 4, g = G & 15;
      int c = (g & 8) | ((g & 7) ^ (r & 7));
      ksrc[i] = (const char*)(kb + (size_t)(s0i + r) * HDIM) + c * 16; }
    { int r = G >> 3, g = G & 7;
      int c = g ^ (r & 7);
      vsrc[i] = (const char*)(vb + (size_t)r * T_SEQ + s0i) + c * 16; }
  }
  auto stage = [&]() {
    #pragma unroll
    for (int i = 0; i < 4; i++) {
      gload_lds16(ksrc[i], (char*)Ks + (w * 4 + i) * 1024);
      ksrc[i] -= 64 * HDIM * 2;
      gload_lds16(vsrc[i], (char*)Vs + (w * 4 + i) * 1024);
      vsrc[i] -= 128;
    }
  };

  f32x4 oacc[8];
  #pragma unroll
  for (int jo = 0; jo < 8; jo++) oacc[jo] = (f32x4){0.f, 0.f, 0.f, 0.f};
  f32x4 lacc = (f32x4){0.f, 0.f, 0.f, 0.f};
  float mrow[4];

  stage();
  __syncthreads();                               // drains vmcnt: tile t1-1 resident

  bool first = true;
  for (int t = t1 - 1; t >= t0; --t) {
    const int s0 = t * 64;

    // S = Q @ K^T   (16 x 64 per wave), log2 domain
    f32x4 sacc[4];
    #pragma unroll
    for (int jf = 0; jf < 4; jf++) sacc[jf] = (f32x4){0.f, 0.f, 0.f, 0.f};
    __builtin_amdgcn_s_setprio(1);
    #pragma unroll
    for (int ks = 0; ks < 4; ks++) {
      #pragma unroll
      for (int jf = 0; jf < 4; jf++) {
        int s = jf * 16 + lo;
        int byteoff = s * 256 + ((ks * 64 + hi * 16) ^ ((s & 7) << 4));
        bf16x8 kf = *(const bf16x8*)((const char*)Ks + byteoff);
        sacc[jf] = __builtin_amdgcn_mfma_f32_16x16x32_bf16(qf[ks], kf, sacc[jf], 0, 0, 0);
      }
    }
    __builtin_amdgcn_s_setprio(0);

    // bias + causal mask
    float sv[4][4];
    #pragma unroll
    for (int jf = 0; jf < 4; jf++) {
      #pragma unroll
      for (int rg = 0; rg < 4; rg++) {
        int i_ = q0 + w * 16 + hi * 4 + rg;
        int j_ = s0 + jf * 16 + lo;
        int d = i_ - j_;
        sv[jf][rg] = (d >= 0) ? (sacc[jf][rg] + bias_tab[d]) : -1e30f;
      }
    }

    // fixed-m: compute row max ONLY on the first (diagonal-most) tile of this chunk.
    // Later tiles have decaying bias; P=exp2(sv-m) stays bounded (<2^15), fp32-safe.
    if (first) {
      #pragma unroll
      for (int rg = 0; rg < 4; rg++) {
        float v = fmaxf(fmaxf(sv[0][rg], sv[1][rg]), fmaxf(sv[2][rg], sv[3][rg]));
        v = fmaxf(v, __shfl_xor(v, 1));
        v = fmaxf(v, __shfl_xor(v, 2));
        v = fmaxf(v, __shfl_xor(v, 4));
        v = fmaxf(v, __shfl_xor(v, 8));
        mrow[rg] = v;
      }
      first = false;
    }

    // P = exp2(sv - m) -> bf16 into per-wave LDS (A-layout bounce); no psum
    #pragma unroll
    for (int jf = 0; jf < 4; jf++) {
      #pragma unroll
      for (int rg = 0; rg < 4; rg++) {
        float p = exp2fast(sv[jf][rg] - mrow[rg]);
        int prow = hi * 4 + rg;
        int pcol = jf * 16 + lo;
        int byteoff = prow * 128 + ((pcol * 2) ^ ((prow & 7) << 4));
        *(short*)((char*)Ps[w] + byteoff) = f2bf(p);
      }
    }

    // O += P @ V ; l += P @ ones  (row sum via MFMA, every lane gets it)
    __builtin_amdgcn_s_setprio(1);
    #pragma unroll
    for (int ks = 0; ks < 2; ks++) {
      int pbyte = lo * 128 + ((ks * 64 + hi * 16) ^ ((lo & 7) << 4));
      bf16x8 pf = *(const bf16x8*)((const char*)Ps[w] + pbyte);
      lacc = __builtin_amdgcn_mfma_f32_16x16x32_bf16(pf, ones, lacc, 0, 0, 0);
      #pragma unroll
      for (int jo = 0; jo < 8; jo++) {
        int h = jo * 16 + lo;
        int vbyte = h * 128 + ((ks * 64 + hi * 16) ^ ((h & 7) << 4));
        bf16x8 vf = *(const bf16x8*)((const char*)Vs + vbyte);
        oacc[jo] = __builtin_amdgcn_mfma_f32_16x16x32_bf16(pf, vf, oacc[jo], 0, 0, 0);
      }
    }
    __builtin_amdgcn_s_setprio(0);

    if (t > t0) {
      __syncthreads();                           // all waves done reading Ks/Vs
      stage();                                   // refill with tile t-1
      __syncthreads();                           // drains vmcnt: tile t-1 resident
    }
  }

  if constexpr (SP == 1) {
    #pragma unroll
    for (int jo = 0; jo < 8; jo++) {
      #pragma unroll
      for (int rg = 0; rg < 4; rg++) {
        int t = q0 + w * 16 + hi * 4 + rg;
        out[((size_t)b * T_SEQ + t) * HDIM + jo * 16 + lo] = oacc[jo][rg] / lacc[rg];
      }
    }
  } else {
    #pragma unroll
    for (int jo = 0; jo < 8; jo++) {
      #pragma unroll
      for (int rg = 0; rg < 4; rg++) {
        int t = q0 + w * 16 + hi * 4 + rg;
        opart[(((size_t)sp * NB + b) * T_SEQ + t) * HDIM + jo * 16 + lo] = f2bf(oacc[jo][rg]);
      }
    }
    if (lo == 0) {
      #pragma unroll
      for (int rg = 0; rg < 4; rg++) {
        int t = q0 + w * 16 + hi * 4 + rg;
        ml[((size_t)sp * NB + b) * T_SEQ + t] = make_float2(mrow[rg], lacc[rg]);
      }
    }
  }
}

// ---------------- merge of S-split partials (exp2 domain, bf16 partials) ---------------
template <int SP>
__global__ __launch_bounds__(256) void msta_merge_kernel(
    const short* __restrict__ opart, const float2* __restrict__ ml,
    float* __restrict__ out) {
  int id  = blockIdx.x * 256 + threadIdx.x;   // [0, NB*T_SEQ*32)
  int row = id >> 5;                          // b*T_SEQ + t
  int c4  = id & 31;

  float2 v[SP];
  float m = -1e30f;
  #pragma unroll
  for (int sp = 0; sp < SP; sp++) {
    v[sp] = ml[(size_t)sp * (NB * T_SEQ) + row];
    if (v[sp].y > 0.f) m = fmaxf(m, v[sp].x);
  }
  float denom = 0.f;
  float wgt[SP];
  #pragma unroll
  for (int sp = 0; sp < SP; sp++) {
    wgt[sp] = (v[sp].y > 0.f) ? exp2fast(v[sp].x - m) : 0.f;
    denom += wgt[sp] * v[sp].y;
  }
  float4 acc = {0.f, 0.f, 0.f, 0.f};
  #pragma unroll
  for (int sp = 0; sp < SP; sp++) {
    if (wgt[sp] != 0.f) {
      ushort4 o = *(const ushort4*)(opart + ((size_t)sp * (NB * T_SEQ) + row) * HDIM + c4 * 4);
      acc.x += wgt[sp] * bf2f((short)o.x); acc.y += wgt[sp] * bf2f((short)o.y);
      acc.z += wgt[sp] * bf2f((short)o.z); acc.w += wgt[sp] * bf2f((short)o.w);
    }
  }
  float inv = 1.f / denom;
  float4 r = make_float4(acc.x * inv, acc.y * inv, acc.z * inv, acc.w * inv);
  *(float4*)(out + (size_t)row * HDIM + c4 * 4) = r;
}

extern "C" void kernel_launch(void* const* d_in, const int* in_sizes, int n_in,
                              void* d_out, int out_size, void* d_ws, size_t ws_size,
                              hipStream_t stream) {
  (void)in_sizes; (void)n_in; (void)out_size;
  const float* x   = (const float*)d_in[0];
  const float* Wq  = (const float*)d_in[1];
  const float* Wk  = (const float*)d_in[2];
  const float* Wv  = (const float*)d_in[3];
  const float* gfl = (const float*)d_in[4];
  const float* gml = (const float*)d_in[5];
  const float* gsl = (const float*)d_in[6];
  const float* al  = (const float*)d_in[7];
  float* out = (float*)d_out;

  // ws layout (bytes):
  //   bias f32[2048]              @ 0
  //   q    bf16[8*2048*128]       @ 8192
  //   k    bf16                   @ 8192 + 4 MiB
  //   vt   bf16                   @ 8192 + 8 MiB
  //   wt   bf16[3*128*1024]       @ 8192 + 12 MiB  (768 KiB)
  //   opart bf16[SP][8*2048][128] @ 13639680       (SP x 4 MiB)
  //   ml    float2[SP][8*2048]    @ after opart    (SP x 128 KiB)
  char* wsb = (char*)d_ws;
  float*  bias_tab = (float*)wsb;
  short*  qw   = (short*)(wsb + 8192);
  short*  kw   = (short*)(wsb + 8192 + 1 * 4194304);
  short*  vtw  = (short*)(wsb + 8192 + 2 * 4194304);
  short*  wtw  = (short*)(wsb + 8192 + 3 * 4194304);
  short*  opart = (short*)(wsb + 13639680);

  const size_t need8 = 13639680 + 8ull * 4194304 + 8ull * 131072;   // ~48.2 MB (proven)
  const size_t need4 = 13639680 + 4ull * 4194304 + 4ull * 131072;   // ~31.0 MB

  msta_bias_kernel<<<8, 256, 0, stream>>>(gfl, gml, gsl, al, bias_tab);
  msta_wt_kernel<<<1536, 256, 0, stream>>>(Wq, Wk, Wv, wtw);
  msta_qkv_kernel<<<768, 256, 0, stream>>>(x, wtw, qw, kw, vtw);

  if (ws_size >= need8) {
    float2* mlp = (float2*)(wsb + 13639680 + 8ull * 4194304);
    msta_attn_kernel<8><<<NB * NQB * 8, 256, 0, stream>>>(qw, kw, vtw, bias_tab,
                                                          nullptr, opart, mlp);
    msta_merge_kernel<8><<<(NB * T_SEQ * 32) / 256, 256, 0, stream>>>(opart, mlp, out);
  } else if (ws_size >= need4) {
    float2* mlp = (float2*)(wsb + 13639680 + 4ull * 4194304);
    msta_attn_kernel<4><<<NB * NQB * 4, 256, 0, stream>>>(qw, kw, vtw, bias_tab,
                                                          nullptr, opart, mlp);
    msta_merge_kernel<4><<<(NB * T_SEQ * 32) / 256, 256, 0, stream>>>(opart, mlp, out);
  } else {
    msta_attn_kernel<1><<<NB * NQB, 256, 0, stream>>>(qw, kw, vtw, bias_tab,
                                                      out, nullptr, nullptr);
  }
}